// Round 11
// baseline (510.309 us; speedup 1.0000x reference)
//
#include <hip/hip_runtime.h>
#include <hip/hip_bf16.h>

// f32 in/out. All intermediates bf16 (f32 accumulation). GEMMs = MFMA
// 16x16x32_bf16 with PRE-TRANSPOSED weights in global (WT[n][K], L2-hot 86KB):
// B-frags are contiguous 16B global loads -> no LDS staging, no barriers.
// k_mlp fuses P1->relu->P2->relu->dotP3->sigmoid (LDS bf16 round-trip, bit-
// identical to the old A1 global round-trip). k_csr also emits x0 (fused
// scale0); k_histK also converts weights. Aggs = round-9 exact unpack+add
// (round-8 lesson: fdot2 rounding blew the budget; round-10 pk_add neutral).
// k_agg<128> is at its structural floor: FETCH ~0.8 * 8 XCD * table size.

typedef unsigned short u16;
typedef unsigned int   u32;
typedef __attribute__((ext_vector_type(8))) short short8;
typedef __attribute__((ext_vector_type(4))) float f32x4;

__device__ __forceinline__ float b2f(u16 u){
  union { u32 i; float f; } c; c.i = ((u32)u) << 16; return c.f;
}
__device__ __forceinline__ u16 f2b(float f){
  union { float f; u32 i; } c; c.f = f;
  u32 x = c.i;
  u32 r = x + 0x7FFFu + ((x >> 16) & 1u);   // round-to-nearest-even
  return (u16)(r >> 16);
}

// exact bf16-pair accumulate: a[0..7] += dims of uint4 (8 bf16)
__device__ __forceinline__ void acc8(uint4 u, float* a){
  a[0] += b2f((u16)(u.x & 0xffff)); a[1] += b2f((u16)(u.x >> 16));
  a[2] += b2f((u16)(u.y & 0xffff)); a[3] += b2f((u16)(u.y >> 16));
  a[4] += b2f((u16)(u.z & 0xffff)); a[5] += b2f((u16)(u.z >> 16));
  a[6] += b2f((u16)(u.w & 0xffff)); a[7] += b2f((u16)(u.w >> 16));
}

// weight layout (bf16, transposed WT[n*K+k]):
//   WT1 @0     : 128x64   (W1)
//   WT2 @8192  : 128x128  (W2)
//   WT3 @24576 : 64x128   (W3)
//   WT4 @32768 : 64x128   (P1)
//   WT5 @40960 : 32x64    (P2)   total 43008 u16
#define NWT 43008

// ---------------- hist (+ weight transpose-convert) ----------------

__global__ __launch_bounds__(256) void k_histK(const int* __restrict__ dst, int ne, int K,
    u32* __restrict__ bhist,
    const float* __restrict__ W1, const float* __restrict__ W2, const float* __restrict__ W3,
    const float* __restrict__ P1, const float* __restrict__ P2, u16* __restrict__ WT){
  extern __shared__ u32 sh[];
  int t = threadIdx.x;
  // fused weight f32 -> bf16 transpose (independent of hist work)
  for (int i = blockIdx.x*256 + t; i < NWT; i += gridDim.x*256){
    float v;
    if (i < 8192)      { int j=i;        v = W1[(j%64)*128 + j/64];   }
    else if (i < 24576){ int j=i-8192;   v = W2[(j%128)*128 + j/128]; }
    else if (i < 32768){ int j=i-24576;  v = W3[(j%128)*64 + j/128];  }
    else if (i < 40960){ int j=i-32768;  v = P1[(j%128)*64 + j/128];  }
    else               { int j=i-40960;  v = P2[(j%64)*32 + j/64];    }
    WT[i] = f2b(v);
  }
  for (int i = t; i < K; i += 256) sh[i] = 0;
  __syncthreads();
  for (int i = blockIdx.x*256 + t; i < ne; i += gridDim.x*256)
    atomicAdd(&sh[dst[i] >> 8], 1u);
  __syncthreads();
  int rot = (int)((blockIdx.x * 73u) % (u32)K);
  for (int jj = t; jj < K; jj += 256){
    int i = jj + rot; if (i >= K) i -= K;
    u32 v = sh[i];
    if (v) atomicAdd(&bhist[i], v);
  }
}

__global__ __launch_bounds__(256) void k_scanK(const u32* __restrict__ bhist, int K,
                                               u32* __restrict__ bbase, u32* __restrict__ gcur){
  __shared__ u32 s[256];
  int t = threadIdx.x;
  int items = (K + 255) / 256;
  u32 local[16];
  int s0 = t * items;
  u32 sum = 0;
  for (int j = 0; j < items; j++){
    int idx = s0 + j;
    u32 v = (idx < K) ? bhist[idx] : 0;
    local[j] = v; sum += v;
  }
  s[t] = sum; __syncthreads();
  for (int off = 1; off < 256; off <<= 1){
    u32 add = (t >= off) ? s[t-off] : 0;
    __syncthreads();
    s[t] += add;
    __syncthreads();
  }
  u32 run = s[t] - sum;
  for (int j = 0; j < items; j++){
    int idx = s0 + j;
    if (idx < K){ bbase[idx] = run; gcur[idx] = run; }
    run += local[j];
  }
  if (t == 255) bbase[K] = s[255];
}

__global__ __launch_bounds__(256) void k_scatterR(const int* __restrict__ src, const int* __restrict__ dst,
                                                  int ne, int K, u32* __restrict__ gcur,
                                                  u32* __restrict__ ebuf){
  extern __shared__ u32 cnt[];
  int t = threadIdx.x;
  int e0 = blockIdx.x * 4096;
  for (int i = t; i < K; i += 256) cnt[i] = 0;
  __syncthreads();
#pragma unroll
  for (int j = 0; j < 16; j++){
    int e = e0 + j*256 + t;
    if (e < ne) atomicAdd(&cnt[dst[e] >> 8], 1u);
  }
  __syncthreads();
  int rot = (int)((blockIdx.x * 73u) % (u32)K);
  for (int jj = t; jj < K; jj += 256){
    int i = jj + rot; if (i >= K) i -= K;
    u32 c = cnt[i];
    if (c) cnt[i] = atomicAdd(&gcur[i], c);
  }
  __syncthreads();
#pragma unroll
  for (int j = 0; j < 16; j++){
    int e = e0 + j*256 + t;
    if (e < ne){
      int d = dst[e];
      u32 p = atomicAdd(&cnt[d >> 8], 1u);
      ebuf[p] = ((u32)(d & 255) << 18) | (u32)src[e];
    }
  }
}

// one block per 256-node bucket: row_ptr + r + col; fused x0 = table*r (bf16)
__global__ __launch_bounds__(256) void k_csr(const u32* __restrict__ ebuf, const u32* __restrict__ bbase,
                                             int n, int ne, int* __restrict__ row_ptr,
                                             float* __restrict__ r, int* __restrict__ col,
                                             const float* __restrict__ ut, const float* __restrict__ it,
                                             int nu, u16* __restrict__ x0){
  __shared__ u32 cnt[256];
  __shared__ u32 pfx[256];
  __shared__ u32 cur[256];
  __shared__ float rsh[256];
  int b = blockIdx.x, t = threadIdx.x;
  u32 bb = bbase[b], be = bbase[b+1];
  int nbase = b << 8;
  int nn = n - nbase; if (nn > 256) nn = 256;
  cnt[t] = 0;
  __syncthreads();
  for (u32 e = bb + t; e < be; e += 256)
    atomicAdd(&cnt[ebuf[e] >> 18], 1u);
  __syncthreads();
  pfx[t] = cnt[t];
  __syncthreads();
  for (int off = 1; off < 256; off <<= 1){
    u32 add = (t >= off) ? pfx[t-off] : 0;
    __syncthreads();
    pfx[t] += add;
    __syncthreads();
  }
  u32 excl = pfx[t] - cnt[t];
  cur[t] = bb + excl;
  if (t < nn){
    float rv = rsqrtf(fmaxf((float)cnt[t], 1.0f));
    row_ptr[nbase + t] = (int)(bb + excl);
    r[nbase + t] = rv;
    rsh[t] = rv;
  }
  __syncthreads();
  for (u32 e = bb + t; e < be; e += 256){
    u32 v = ebuf[e];
    u32 p = atomicAdd(&cur[v >> 18], 1u);
    col[p] = (int)(v & 0x3FFFFu);
  }
  if (b == 0 && t == 0) row_ptr[n] = ne;
  // fused x0 (bit-identical to old k_scale0): 16 float4 chunks per node
  for (int i = t; i < nn*16; i += 256){
    int ln = i >> 4;
    int node = nbase + ln;
    int c4 = (i & 15) << 2;
    float rv = rsh[ln];
    const float* srcp = (node < nu) ? (ut + (size_t)node*64 + c4)
                                    : (it + (size_t)(node-nu)*64 + c4);
    float4 v = *(const float4*)srcp;
    ushort4 o;
    o.x = f2b(v.x*rv); o.y = f2b(v.y*rv); o.z = f2b(v.z*rv); o.w = f2b(v.w*rv);
    *(ushort4*)(x0 + (size_t)node*64 + c4) = o;
  }
}

// ---------------- aggregation: one wave per node, G-lane edge groups ----------------
// G = D/8 lanes per edge (uint4 = 8 bf16). E = 64/G edge groups; 2-edge unroll.
template<int D, bool BIAS>
__global__ __launch_bounds__(256) void k_agg(const u16* __restrict__ x, const float* __restrict__ r,
    const int* __restrict__ row_ptr, const int* __restrict__ col,
    const float* __restrict__ bias, u16* __restrict__ out, int n){
  constexpr int G = D/8;
  constexpr int E = 64/G;
  int wid = (blockIdx.x*256 + threadIdx.x) >> 6;
  int lane = threadIdx.x & 63;
  if (wid >= n) return;
  int gidx = lane / G;
  int l    = lane % G;
  int beg = row_ptr[wid], end = row_ptr[wid+1];
  float a[8] = {0.f,0.f,0.f,0.f,0.f,0.f,0.f,0.f};
  int e = beg + gidx;
  for (; e + E < end; e += 2*E){
    int s0 = col[e];
    int s1 = col[e+E];
    uint4 u0 = *(const uint4*)(x + (size_t)s0*D + l*8);
    uint4 u1 = *(const uint4*)(x + (size_t)s1*D + l*8);
    acc8(u0, a);
    acc8(u1, a);
  }
  if (e < end){
    int s = col[e];
    acc8(*(const uint4*)(x + (size_t)s*D + l*8), a);
  }
#pragma unroll
  for (int off = G; off < 64; off <<= 1){
#pragma unroll
    for (int i = 0; i < 8; i++) a[i] += __shfl_xor(a[i], off);
  }
  if (gidx == 0){
    float rn = r[wid];
    float v[8];
#pragma unroll
    for (int i = 0; i < 8; i++){
      float y = a[i] * rn;
      if constexpr (BIAS) y += bias[l*8 + i];
      v[i] = y;
    }
    uint4 o;
    o.x = (u32)f2b(v[0]) | ((u32)f2b(v[1]) << 16);
    o.y = (u32)f2b(v[2]) | ((u32)f2b(v[3]) << 16);
    o.z = (u32)f2b(v[4]) | ((u32)f2b(v[5]) << 16);
    o.w = (u32)f2b(v[6]) | ((u32)f2b(v[7]) << 16);
    *(uint4*)(out + (size_t)wid*D + l*8) = o;
  }
}

// ---------------- MFMA GEMM: C[nrows,OUT] = act(A[nrows,K_] @ W + b) * r ----------------
// 256 thr = 4 waves x 32 rows (2 m-tiles), block 128 rows. A bf16 row-major,
// direct global->VGPR A-frags; B-frags direct from global WT[n*K_+k] (L2-hot).
// No LDS, no barriers.
template<int K_, int OUT, bool BIAS, bool RELU, bool SCALE>
__global__ __launch_bounds__(256) void k_mgemm(
    const u16* __restrict__ A, const u16* __restrict__ WT, const float* __restrict__ bias,
    const float* __restrict__ rr, u16* __restrict__ C, int nrows)
{
  constexpr int NT = OUT / 16;
  constexpr int KS = K_ / 32;
  const int t = threadIdx.x;
  const int wave = t >> 6, lane = t & 63;
  const int quad = lane >> 4, m16 = lane & 15;
  const int rowb = blockIdx.x*128 + wave*32;

  const short8 zz = {0,0,0,0,0,0,0,0};
  short8 afr[2][KS];
#pragma unroll
  for (int mt = 0; mt < 2; mt++){
    int row = rowb + mt*16 + m16;
    bool ok = row < nrows;
#pragma unroll
    for (int ks = 0; ks < KS; ks++){
      afr[mt][ks] = ok ? *(const short8*)(A + (size_t)row*K_ + ks*32 + quad*8) : zz;
    }
  }

  f32x4 acc[2][NT];
#pragma unroll
  for (int mt = 0; mt < 2; mt++)
#pragma unroll
    for (int nt = 0; nt < NT; nt++) acc[mt][nt] = (f32x4){0.f,0.f,0.f,0.f};

#pragma unroll
  for (int nt = 0; nt < NT; nt++){
#pragma unroll
    for (int ks = 0; ks < KS; ks++){
      short8 b = *(const short8*)(WT + (size_t)(nt*16 + m16)*K_ + ks*32 + quad*8);
      acc[0][nt] = __builtin_amdgcn_mfma_f32_16x16x32_bf16(afr[0][ks], b, acc[0][nt], 0, 0, 0);
      acc[1][nt] = __builtin_amdgcn_mfma_f32_16x16x32_bf16(afr[1][ks], b, acc[1][nt], 0, 0, 0);
    }
  }

  float bv[NT];
#pragma unroll
  for (int nt = 0; nt < NT; nt++){
    if constexpr (BIAS) bv[nt] = bias[nt*16 + m16]; else bv[nt] = 0.f;
  }
#pragma unroll
  for (int mt = 0; mt < 2; mt++){
    int row0 = rowb + mt*16 + quad*4;
#pragma unroll
    for (int reg = 0; reg < 4; reg++){
      int row = row0 + reg;
      if (row >= nrows) continue;
      float rs = 1.f;
      if constexpr (SCALE) rs = rr[row];
#pragma unroll
      for (int nt = 0; nt < NT; nt++){
        float v = acc[mt][nt][reg];
        if constexpr (BIAS) v += bv[nt];
        if constexpr (RELU) v = fmaxf(v, 0.f);
        if constexpr (SCALE) v *= rs;
        C[(size_t)row*OUT + nt*16 + m16] = f2b(v);
      }
    }
  }
}

// ---------------- fused MLP: sigmoid(relu(relu(z P1+pb1) P2+pb2) . P3 + pb3) ----------------
// z[row] = concat(x3[uidx[row]], x3[nu+vidx[row]]) gathered as K=128 A-frags.
// Stage1 MFMA (OUT=64) -> relu -> bf16 LDS (stride 72: <=2-way conflicts) ->
// stage2 A-frags -> MFMA (OUT=32) -> P3-dot (quad shfl) -> sigmoid -> f32 out.
__global__ __launch_bounds__(256) void k_mlp(
    const u16* __restrict__ x3, const u16* __restrict__ WT4, const float* __restrict__ pb1v,
    const u16* __restrict__ WT5, const float* __restrict__ pb2v,
    const float* __restrict__ P3, const float* __restrict__ pb3,
    const int* __restrict__ uidx, const int* __restrict__ vidx,
    int B, int nu, float* __restrict__ outp)
{
  __shared__ u16 a1[128*72];
  const int t = threadIdx.x;
  const int wave = t >> 6, lane = t & 63;
  const int quad = lane >> 4, m16 = lane & 15;
  const int rowb = blockIdx.x*128 + wave*32;

  // stage 1: K=128 gathered A, OUT=64
  const short8 zz = {0,0,0,0,0,0,0,0};
  short8 afr[2][4];
#pragma unroll
  for (int mt = 0; mt < 2; mt++){
    int row = rowb + mt*16 + m16;
    bool ok = row < B;
#pragma unroll
    for (int ks = 0; ks < 4; ks++){
      int k = ks*32 + quad*8;
      if (!ok){ afr[mt][ks] = zz; continue; }
      int node, kk;
      if (k < 64){ node = uidx[row];      kk = k; }
      else       { node = nu + vidx[row]; kk = k - 64; }
      afr[mt][ks] = *(const short8*)(x3 + (size_t)node*64 + kk);
    }
  }
  f32x4 acc[2][4];
#pragma unroll
  for (int mt = 0; mt < 2; mt++)
#pragma unroll
    for (int nt = 0; nt < 4; nt++) acc[mt][nt] = (f32x4){0.f,0.f,0.f,0.f};
#pragma unroll
  for (int nt = 0; nt < 4; nt++){
#pragma unroll
    for (int ks = 0; ks < 4; ks++){
      short8 b = *(const short8*)(WT4 + (size_t)(nt*16 + m16)*128 + ks*32 + quad*8);
      acc[0][nt] = __builtin_amdgcn_mfma_f32_16x16x32_bf16(afr[0][ks], b, acc[0][nt], 0, 0, 0);
      acc[1][nt] = __builtin_amdgcn_mfma_f32_16x16x32_bf16(afr[1][ks], b, acc[1][nt], 0, 0, 0);
    }
  }
  // epilogue 1 -> LDS (bf16, bit-identical to old global A1 round-trip)
  float pb1s[4];
#pragma unroll
  for (int nt = 0; nt < 4; nt++) pb1s[nt] = pb1v[nt*16 + m16];
#pragma unroll
  for (int mt = 0; mt < 2; mt++){
    int rl0 = wave*32 + mt*16 + quad*4;
#pragma unroll
    for (int reg = 0; reg < 4; reg++){
#pragma unroll
      for (int nt = 0; nt < 4; nt++){
        float v = fmaxf(acc[mt][nt][reg] + pb1s[nt], 0.f);
        a1[(rl0 + reg)*72 + nt*16 + m16] = f2b(v);
      }
    }
  }
  __syncthreads();

  // stage 2: A from LDS, K=64, OUT=32
  short8 af2[2][2];
#pragma unroll
  for (int mt = 0; mt < 2; mt++){
    int rl = wave*32 + mt*16 + m16;
#pragma unroll
    for (int ks = 0; ks < 2; ks++)
      af2[mt][ks] = *(const short8*)(a1 + rl*72 + ks*32 + quad*8);
  }
  f32x4 acc2[2][2];
#pragma unroll
  for (int mt = 0; mt < 2; mt++)
#pragma unroll
    for (int nt = 0; nt < 2; nt++) acc2[mt][nt] = (f32x4){0.f,0.f,0.f,0.f};
#pragma unroll
  for (int nt = 0; nt < 2; nt++){
#pragma unroll
    for (int ks = 0; ks < 2; ks++){
      short8 b = *(const short8*)(WT5 + (size_t)(nt*16 + m16)*64 + ks*32 + quad*8);
      acc2[0][nt] = __builtin_amdgcn_mfma_f32_16x16x32_bf16(af2[0][ks], b, acc2[0][nt], 0, 0, 0);
      acc2[1][nt] = __builtin_amdgcn_mfma_f32_16x16x32_bf16(af2[1][ks], b, acc2[1][nt], 0, 0, 0);
    }
  }
  // epilogue 2: relu -> dot P3 across 32 cols -> sigmoid
  float b0 = pb2v[m16], b1v = pb2v[16 + m16];
  float p0 = P3[m16],   p1 = P3[16 + m16];
  float pb = pb3[0];
#pragma unroll
  for (int mt = 0; mt < 2; mt++){
    float v4[4];
#pragma unroll
    for (int reg = 0; reg < 4; reg++){
      float part = fmaxf(acc2[mt][0][reg] + b0, 0.f) * p0
                 + fmaxf(acc2[mt][1][reg] + b1v, 0.f) * p1;
      part += __shfl_xor(part, 1);
      part += __shfl_xor(part, 2);
      part += __shfl_xor(part, 4);
      part += __shfl_xor(part, 8);
      v4[reg] = 1.f / (1.f + __expf(-(part + pb)));
    }
    if (m16 == 0){
      int row0 = rowb + mt*16 + quad*4;
      if (row0 + 3 < B){
        *(float4*)(outp + row0) = make_float4(v4[0], v4[1], v4[2], v4[3]);
      } else {
#pragma unroll
        for (int reg = 0; reg < 4; reg++)
          if (row0 + reg < B) outp[row0 + reg] = v4[reg];
      }
    }
  }
}

// ---------------- launcher ----------------

extern "C" void kernel_launch(void* const* d_in, const int* in_sizes, int n_in,
                              void* d_out, int out_size, void* d_ws, size_t ws_size,
                              hipStream_t stream){
  const float* ut  = (const float*)d_in[0];
  const float* it  = (const float*)d_in[1];
  const float* W1  = (const float*)d_in[2];
  const float* b1  = (const float*)d_in[3];
  const float* W2  = (const float*)d_in[4];
  const float* b2  = (const float*)d_in[5];
  const float* W3  = (const float*)d_in[6];
  const float* b3  = (const float*)d_in[7];
  const float* P1  = (const float*)d_in[8];
  const float* pb1 = (const float*)d_in[9];
  const float* P2  = (const float*)d_in[10];
  const float* pb2 = (const float*)d_in[11];
  const float* P3  = (const float*)d_in[12];
  const float* pb3 = (const float*)d_in[13];
  const int* src  = (const int*)d_in[14];
  const int* dst  = (const int*)d_in[15];
  const int* uidx = (const int*)d_in[16];
  const int* vidx = (const int*)d_in[17];

  const int NU = in_sizes[0] / 64;
  const int NI = in_sizes[1] / 64;
  const int N  = NU + NI;
  const int NE = in_sizes[14];
  const int B  = in_sizes[16];
  const int K  = (N + 255) >> 8;

  char* w = (char*)d_ws;
  auto alloc = [&](size_t bytes)->void*{
    void* p = (void*)w;
    w += (bytes + 255) & ~(size_t)255;
    return p;
  };
  float* r       = (float*)alloc((size_t)N*4);
  int*   row_ptr = (int*)  alloc((size_t)(N+1)*4);
  u32*   bhist   = (u32*)  alloc((size_t)K*4);
  u32*   bbase   = (u32*)  alloc((size_t)(K+1)*4);
  u32*   gcur    = (u32*)  alloc((size_t)K*4);
  int*   col     = (int*)  alloc((size_t)NE*4);
  u16*   Wall    = (u16*)  alloc((size_t)NWT*2);
  char*  bufE    = (char*) alloc((size_t)N*64*2 > (size_t)NE*4 ? (size_t)N*64*2 : (size_t)NE*4);
                                                      // ebuf(u32,NE) -> m1(bf16) -> x3(bf16)
  char*  bufF    = (char*) alloc((size_t)N*128*2);    // m2(bf16)
  u16*   bufC    = (u16*)  alloc((size_t)N*128*2);    // h1 -> h2
  u16*   bufD    = (u16*)  alloc((size_t)N*64*2);     // x0 -> g3
  if ((size_t)(w - (char*)d_ws) > ws_size) return;

  u16* WT1 = Wall;            // 128x64
  u16* WT2 = Wall + 8192;     // 128x128
  u16* WT3 = Wall + 24576;    // 64x128
  u16* WT4 = Wall + 32768;    // 64x128 (P1)
  u16* WT5 = Wall + 40960;    // 32x64  (P2)

  u32* ebuf = (u32*)bufE;
  u16* x0   = bufD;

  hipMemsetAsync(bhist, 0, (size_t)K*4, stream);

  int g;
  k_histK  <<<128, 256, (size_t)K*4, stream>>>(dst, NE, K, bhist, W1, W2, W3, P1, P2, Wall);
  k_scanK  <<<1, 256, 0, stream>>>(bhist, K, bbase, gcur);
  g = (NE + 4095)/4096;
  k_scatterR<<<g, 256, (size_t)K*4, stream>>>(src, dst, NE, K, gcur, ebuf);
  k_csr    <<<K, 256, 0, stream>>>(ebuf, bbase, N, NE, row_ptr, r, col, ut, it, NU, x0);

  const int ga  = (N + 3)/4;
  const int gN  = (N + 127)/128;
  const int gB  = (B + 127)/128;

  u16* m1 = (u16*)bufE;               // ebuf dead after k_csr
  k_agg<64,false><<<ga,256,0,stream>>>(x0, r, row_ptr, col, nullptr, m1, N);
  u16* h1 = bufC;
  k_mgemm<64,128,true,true,true><<<gN,256,0,stream>>>(m1, WT1, b1, r, h1, N);

  u16* m2 = (u16*)bufF;
  k_agg<128,false><<<ga,256,0,stream>>>(h1, r, row_ptr, col, nullptr, m2, N);
  u16* h2 = bufC;                     // h1 dead after agg
  k_mgemm<128,128,true,true,true><<<gN,256,0,stream>>>(m2, WT2, b2, r, h2, N);

  u16* g3 = bufD;                     // x0 dead after first agg
  k_mgemm<128,64,false,false,false><<<gN,256,0,stream>>>(h2, WT3, nullptr, nullptr, g3, N);

  u16* x3 = (u16*)bufE;               // m1 dead after GEMM1
  k_agg<64,true><<<ga,256,0,stream>>>(g3, r, row_ptr, col, b3, x3, N);

  k_mlp<<<gB,256,0,stream>>>(x3, WT4, pb1, WT5, pb2, P3, pb3, uidx, vidx, B, NU, (float*)d_out);
}

// Round 12
// 487.506 us; speedup vs baseline: 1.0468x; 1.0468x over previous
//
#include <hip/hip_runtime.h>
#include <hip/hip_bf16.h>

// f32 in/out. All intermediates bf16 (f32 accumulation). GEMMs = MFMA
// 16x16x32_bf16. Weights pre-transposed in global (WT[n][K]) by k_histK, then
// staged into PADDED LDS per block via straight coalesced 16B copies (round-11
// lesson: B-frags direct from global = 16 scattered 64B L2 transactions per
// wave -> L2-request-bound, 23us regression; round-9 lesson: LDS staging works
// but in-kernel transpose is the wasteful part). k_mlp fuses P1->relu->P2->
// relu->dotP3->sigmoid. k_csr emits x0 (fused scale0). Aggs = exact unpack+add
// (round-8: fdot2 rounding blew budget; round-10: pk_add neutral). k_agg<128>
// at structural floor: FETCH ~0.8 * 8 XCD * table size.

typedef unsigned short u16;
typedef unsigned int   u32;
typedef __attribute__((ext_vector_type(8))) short short8;
typedef __attribute__((ext_vector_type(4))) float f32x4;

__device__ __forceinline__ float b2f(u16 u){
  union { u32 i; float f; } c; c.i = ((u32)u) << 16; return c.f;
}
__device__ __forceinline__ u16 f2b(float f){
  union { float f; u32 i; } c; c.f = f;
  u32 x = c.i;
  u32 r = x + 0x7FFFu + ((x >> 16) & 1u);   // round-to-nearest-even
  return (u16)(r >> 16);
}

// exact bf16-pair accumulate: a[0..7] += dims of uint4 (8 bf16)
__device__ __forceinline__ void acc8(uint4 u, float* a){
  a[0] += b2f((u16)(u.x & 0xffff)); a[1] += b2f((u16)(u.x >> 16));
  a[2] += b2f((u16)(u.y & 0xffff)); a[3] += b2f((u16)(u.y >> 16));
  a[4] += b2f((u16)(u.z & 0xffff)); a[5] += b2f((u16)(u.z >> 16));
  a[6] += b2f((u16)(u.w & 0xffff)); a[7] += b2f((u16)(u.w >> 16));
}

// weight layout (bf16, transposed WT[n*K+k]):
//   WT1 @0     : 128x64   (W1)
//   WT2 @8192  : 128x128  (W2)
//   WT3 @24576 : 64x128   (W3)
//   WT4 @32768 : 64x128   (P1)
//   WT5 @40960 : 32x64    (P2)   total 43008 u16
#define NWT 43008

// ---------------- hist (+ weight transpose-convert) ----------------

__global__ __launch_bounds__(256) void k_histK(const int* __restrict__ dst, int ne, int K,
    u32* __restrict__ bhist,
    const float* __restrict__ W1, const float* __restrict__ W2, const float* __restrict__ W3,
    const float* __restrict__ P1, const float* __restrict__ P2, u16* __restrict__ WT){
  extern __shared__ u32 sh[];
  int t = threadIdx.x;
  // fused weight f32 -> bf16 transpose (independent of hist work)
  for (int i = blockIdx.x*256 + t; i < NWT; i += gridDim.x*256){
    float v;
    if (i < 8192)      { int j=i;        v = W1[(j%64)*128 + j/64];   }
    else if (i < 24576){ int j=i-8192;   v = W2[(j%128)*128 + j/128]; }
    else if (i < 32768){ int j=i-24576;  v = W3[(j%128)*64 + j/128];  }
    else if (i < 40960){ int j=i-32768;  v = P1[(j%128)*64 + j/128];  }
    else               { int j=i-40960;  v = P2[(j%64)*32 + j/64];    }
    WT[i] = f2b(v);
  }
  for (int i = t; i < K; i += 256) sh[i] = 0;
  __syncthreads();
  for (int i = blockIdx.x*256 + t; i < ne; i += gridDim.x*256)
    atomicAdd(&sh[dst[i] >> 8], 1u);
  __syncthreads();
  int rot = (int)((blockIdx.x * 73u) % (u32)K);
  for (int jj = t; jj < K; jj += 256){
    int i = jj + rot; if (i >= K) i -= K;
    u32 v = sh[i];
    if (v) atomicAdd(&bhist[i], v);
  }
}

__global__ __launch_bounds__(256) void k_scanK(const u32* __restrict__ bhist, int K,
                                               u32* __restrict__ bbase, u32* __restrict__ gcur){
  __shared__ u32 s[256];
  int t = threadIdx.x;
  int items = (K + 255) / 256;
  u32 local[16];
  int s0 = t * items;
  u32 sum = 0;
  for (int j = 0; j < items; j++){
    int idx = s0 + j;
    u32 v = (idx < K) ? bhist[idx] : 0;
    local[j] = v; sum += v;
  }
  s[t] = sum; __syncthreads();
  for (int off = 1; off < 256; off <<= 1){
    u32 add = (t >= off) ? s[t-off] : 0;
    __syncthreads();
    s[t] += add;
    __syncthreads();
  }
  u32 run = s[t] - sum;
  for (int j = 0; j < items; j++){
    int idx = s0 + j;
    if (idx < K){ bbase[idx] = run; gcur[idx] = run; }
    run += local[j];
  }
  if (t == 255) bbase[K] = s[255];
}

__global__ __launch_bounds__(256) void k_scatterR(const int* __restrict__ src, const int* __restrict__ dst,
                                                  int ne, int K, u32* __restrict__ gcur,
                                                  u32* __restrict__ ebuf){
  extern __shared__ u32 cnt[];
  int t = threadIdx.x;
  int e0 = blockIdx.x * 4096;
  for (int i = t; i < K; i += 256) cnt[i] = 0;
  __syncthreads();
#pragma unroll
  for (int j = 0; j < 16; j++){
    int e = e0 + j*256 + t;
    if (e < ne) atomicAdd(&cnt[dst[e] >> 8], 1u);
  }
  __syncthreads();
  int rot = (int)((blockIdx.x * 73u) % (u32)K);
  for (int jj = t; jj < K; jj += 256){
    int i = jj + rot; if (i >= K) i -= K;
    u32 c = cnt[i];
    if (c) cnt[i] = atomicAdd(&gcur[i], c);
  }
  __syncthreads();
#pragma unroll
  for (int j = 0; j < 16; j++){
    int e = e0 + j*256 + t;
    if (e < ne){
      int d = dst[e];
      u32 p = atomicAdd(&cnt[d >> 8], 1u);
      ebuf[p] = ((u32)(d & 255) << 18) | (u32)src[e];
    }
  }
}

// one block per 256-node bucket: row_ptr + r + col; fused x0 = table*r (bf16)
__global__ __launch_bounds__(256) void k_csr(const u32* __restrict__ ebuf, const u32* __restrict__ bbase,
                                             int n, int ne, int* __restrict__ row_ptr,
                                             float* __restrict__ r, int* __restrict__ col,
                                             const float* __restrict__ ut, const float* __restrict__ it,
                                             int nu, u16* __restrict__ x0){
  __shared__ u32 cnt[256];
  __shared__ u32 pfx[256];
  __shared__ u32 cur[256];
  __shared__ float rsh[256];
  int b = blockIdx.x, t = threadIdx.x;
  u32 bb = bbase[b], be = bbase[b+1];
  int nbase = b << 8;
  int nn = n - nbase; if (nn > 256) nn = 256;
  cnt[t] = 0;
  __syncthreads();
  for (u32 e = bb + t; e < be; e += 256)
    atomicAdd(&cnt[ebuf[e] >> 18], 1u);
  __syncthreads();
  pfx[t] = cnt[t];
  __syncthreads();
  for (int off = 1; off < 256; off <<= 1){
    u32 add = (t >= off) ? pfx[t-off] : 0;
    __syncthreads();
    pfx[t] += add;
    __syncthreads();
  }
  u32 excl = pfx[t] - cnt[t];
  cur[t] = bb + excl;
  if (t < nn){
    float rv = rsqrtf(fmaxf((float)cnt[t], 1.0f));
    row_ptr[nbase + t] = (int)(bb + excl);
    r[nbase + t] = rv;
    rsh[t] = rv;
  }
  __syncthreads();
  for (u32 e = bb + t; e < be; e += 256){
    u32 v = ebuf[e];
    u32 p = atomicAdd(&cur[v >> 18], 1u);
    col[p] = (int)(v & 0x3FFFFu);
  }
  if (b == 0 && t == 0) row_ptr[n] = ne;
  // fused x0 (bit-identical to old k_scale0): 16 float4 chunks per node
  for (int i = t; i < nn*16; i += 256){
    int ln = i >> 4;
    int node = nbase + ln;
    int c4 = (i & 15) << 2;
    float rv = rsh[ln];
    const float* srcp = (node < nu) ? (ut + (size_t)node*64 + c4)
                                    : (it + (size_t)(node-nu)*64 + c4);
    float4 v = *(const float4*)srcp;
    ushort4 o;
    o.x = f2b(v.x*rv); o.y = f2b(v.y*rv); o.z = f2b(v.z*rv); o.w = f2b(v.w*rv);
    *(ushort4*)(x0 + (size_t)node*64 + c4) = o;
  }
}

// ---------------- aggregation: one wave per node, G-lane edge groups ----------------
// G = D/8 lanes per edge (uint4 = 8 bf16). E = 64/G edge groups; 2-edge unroll.
template<int D, bool BIAS>
__global__ __launch_bounds__(256) void k_agg(const u16* __restrict__ x, const float* __restrict__ r,
    const int* __restrict__ row_ptr, const int* __restrict__ col,
    const float* __restrict__ bias, u16* __restrict__ out, int n){
  constexpr int G = D/8;
  constexpr int E = 64/G;
  int wid = (blockIdx.x*256 + threadIdx.x) >> 6;
  int lane = threadIdx.x & 63;
  if (wid >= n) return;
  int gidx = lane / G;
  int l    = lane % G;
  int beg = row_ptr[wid], end = row_ptr[wid+1];
  float a[8] = {0.f,0.f,0.f,0.f,0.f,0.f,0.f,0.f};
  int e = beg + gidx;
  for (; e + E < end; e += 2*E){
    int s0 = col[e];
    int s1 = col[e+E];
    uint4 u0 = *(const uint4*)(x + (size_t)s0*D + l*8);
    uint4 u1 = *(const uint4*)(x + (size_t)s1*D + l*8);
    acc8(u0, a);
    acc8(u1, a);
  }
  if (e < end){
    int s = col[e];
    acc8(*(const uint4*)(x + (size_t)s*D + l*8), a);
  }
#pragma unroll
  for (int off = G; off < 64; off <<= 1){
#pragma unroll
    for (int i = 0; i < 8; i++) a[i] += __shfl_xor(a[i], off);
  }
  if (gidx == 0){
    float rn = r[wid];
    float v[8];
#pragma unroll
    for (int i = 0; i < 8; i++){
      float y = a[i] * rn;
      if constexpr (BIAS) y += bias[l*8 + i];
      v[i] = y;
    }
    uint4 o;
    o.x = (u32)f2b(v[0]) | ((u32)f2b(v[1]) << 16);
    o.y = (u32)f2b(v[2]) | ((u32)f2b(v[3]) << 16);
    o.z = (u32)f2b(v[4]) | ((u32)f2b(v[5]) << 16);
    o.w = (u32)f2b(v[6]) | ((u32)f2b(v[7]) << 16);
    *(uint4*)(out + (size_t)wid*D + l*8) = o;
  }
}

// ---------------- MFMA GEMM: C[nrows,OUT] = act(A[nrows,K_] @ W + b) * r ----------------
// 256 thr = 4 waves x 32 rows (2 m-tiles), block 128 rows. A bf16 row-major,
// direct global->VGPR A-frags. WT (pre-transposed, k-contiguous) staged into
// padded LDS (stride K_+8: 2-way bank aliasing = free) via coalesced 16B copy.
template<int K_, int OUT, bool BIAS, bool RELU, bool SCALE>
__global__ __launch_bounds__(256) void k_mgemm(
    const u16* __restrict__ A, const u16* __restrict__ WT, const float* __restrict__ bias,
    const float* __restrict__ rr, u16* __restrict__ C, int nrows)
{
  constexpr int KP = K_ + 8;
  constexpr int NT = OUT / 16;
  constexpr int KS = K_ / 32;
  constexpr int KC = K_ / 8;          // 16B chunks per row
  __shared__ u16 Ws[OUT * KP];
  const int t = threadIdx.x;

  for (int i = t; i < OUT*KC; i += 256){
    int n = i / KC, kc = (i % KC) * 8;
    *(short8*)(Ws + n*KP + kc) = *(const short8*)(WT + (size_t)n*K_ + kc);
  }
  __syncthreads();

  const int wave = t >> 6, lane = t & 63;
  const int quad = lane >> 4, m16 = lane & 15;
  const int rowb = blockIdx.x*128 + wave*32;

  const short8 zz = {0,0,0,0,0,0,0,0};
  short8 afr[2][KS];
#pragma unroll
  for (int mt = 0; mt < 2; mt++){
    int row = rowb + mt*16 + m16;
    bool ok = row < nrows;
#pragma unroll
    for (int ks = 0; ks < KS; ks++){
      afr[mt][ks] = ok ? *(const short8*)(A + (size_t)row*K_ + ks*32 + quad*8) : zz;
    }
  }

  f32x4 acc[2][NT];
#pragma unroll
  for (int mt = 0; mt < 2; mt++)
#pragma unroll
    for (int nt = 0; nt < NT; nt++) acc[mt][nt] = (f32x4){0.f,0.f,0.f,0.f};

#pragma unroll
  for (int nt = 0; nt < NT; nt++){
#pragma unroll
    for (int ks = 0; ks < KS; ks++){
      short8 b = *(const short8*)(Ws + (size_t)(nt*16 + m16)*KP + ks*32 + quad*8);
      acc[0][nt] = __builtin_amdgcn_mfma_f32_16x16x32_bf16(afr[0][ks], b, acc[0][nt], 0, 0, 0);
      acc[1][nt] = __builtin_amdgcn_mfma_f32_16x16x32_bf16(afr[1][ks], b, acc[1][nt], 0, 0, 0);
    }
  }

  float bv[NT];
#pragma unroll
  for (int nt = 0; nt < NT; nt++){
    if constexpr (BIAS) bv[nt] = bias[nt*16 + m16]; else bv[nt] = 0.f;
  }
#pragma unroll
  for (int mt = 0; mt < 2; mt++){
    int row0 = rowb + mt*16 + quad*4;
#pragma unroll
    for (int reg = 0; reg < 4; reg++){
      int row = row0 + reg;
      if (row >= nrows) continue;
      float rs = 1.f;
      if constexpr (SCALE) rs = rr[row];
#pragma unroll
      for (int nt = 0; nt < NT; nt++){
        float v = acc[mt][nt][reg];
        if constexpr (BIAS) v += bv[nt];
        if constexpr (RELU) v = fmaxf(v, 0.f);
        if constexpr (SCALE) v *= rs;
        C[(size_t)row*OUT + nt*16 + m16] = f2b(v);
      }
    }
  }
}

// ---------------- fused MLP: sigmoid(relu(relu(z P1+pb1) P2+pb2) . P3 + pb3) ----------------
// z[row] = concat(x3[uidx[row]], x3[nu+vidx[row]]) gathered as K=128 A-frags.
// WT4/WT5 staged into padded LDS. Stage1 MFMA (OUT=64) -> relu -> bf16 LDS
// (stride 72) -> stage2 MFMA (OUT=32) -> P3-dot (quad shfl) -> sigmoid -> f32.
__global__ __launch_bounds__(256) void k_mlp(
    const u16* __restrict__ x3, const u16* __restrict__ WT4, const float* __restrict__ pb1v,
    const u16* __restrict__ WT5, const float* __restrict__ pb2v,
    const float* __restrict__ P3, const float* __restrict__ pb3,
    const int* __restrict__ uidx, const int* __restrict__ vidx,
    int B, int nu, float* __restrict__ outp)
{
  __shared__ u16 Ws4[64*136];
  __shared__ u16 Ws5[32*72];
  __shared__ u16 a1[128*72];
  const int t = threadIdx.x;
  const int wave = t >> 6, lane = t & 63;
  const int quad = lane >> 4, m16 = lane & 15;
  const int rowb = blockIdx.x*128 + wave*32;

  for (int i = t; i < 64*16; i += 256){
    int n = i >> 4, kc = (i & 15) * 8;
    *(short8*)(Ws4 + n*136 + kc) = *(const short8*)(WT4 + (size_t)n*128 + kc);
  }
  for (int i = t; i < 32*8; i += 256){
    int n = i >> 3, kc = (i & 7) * 8;
    *(short8*)(Ws5 + n*72 + kc) = *(const short8*)(WT5 + (size_t)n*64 + kc);
  }
  __syncthreads();

  // stage 1: K=128 gathered A, OUT=64
  const short8 zz = {0,0,0,0,0,0,0,0};
  short8 afr[2][4];
#pragma unroll
  for (int mt = 0; mt < 2; mt++){
    int row = rowb + mt*16 + m16;
    bool ok = row < B;
#pragma unroll
    for (int ks = 0; ks < 4; ks++){
      int k = ks*32 + quad*8;
      if (!ok){ afr[mt][ks] = zz; continue; }
      int node, kk;
      if (k < 64){ node = uidx[row];      kk = k; }
      else       { node = nu + vidx[row]; kk = k - 64; }
      afr[mt][ks] = *(const short8*)(x3 + (size_t)node*64 + kk);
    }
  }
  f32x4 acc[2][4];
#pragma unroll
  for (int mt = 0; mt < 2; mt++)
#pragma unroll
    for (int nt = 0; nt < 4; nt++) acc[mt][nt] = (f32x4){0.f,0.f,0.f,0.f};
#pragma unroll
  for (int nt = 0; nt < 4; nt++){
#pragma unroll
    for (int ks = 0; ks < 4; ks++){
      short8 b = *(const short8*)(Ws4 + (size_t)(nt*16 + m16)*136 + ks*32 + quad*8);
      acc[0][nt] = __builtin_amdgcn_mfma_f32_16x16x32_bf16(afr[0][ks], b, acc[0][nt], 0, 0, 0);
      acc[1][nt] = __builtin_amdgcn_mfma_f32_16x16x32_bf16(afr[1][ks], b, acc[1][nt], 0, 0, 0);
    }
  }
  // epilogue 1 -> LDS (bf16, bit-identical to old global A1 round-trip)
  float pb1s[4];
#pragma unroll
  for (int nt = 0; nt < 4; nt++) pb1s[nt] = pb1v[nt*16 + m16];
#pragma unroll
  for (int mt = 0; mt < 2; mt++){
    int rl0 = wave*32 + mt*16 + quad*4;
#pragma unroll
    for (int reg = 0; reg < 4; reg++){
#pragma unroll
      for (int nt = 0; nt < 4; nt++){
        float v = fmaxf(acc[mt][nt][reg] + pb1s[nt], 0.f);
        a1[(rl0 + reg)*72 + nt*16 + m16] = f2b(v);
      }
    }
  }
  __syncthreads();

  // stage 2: A from LDS, K=64, OUT=32
  short8 af2[2][2];
#pragma unroll
  for (int mt = 0; mt < 2; mt++){
    int rl = wave*32 + mt*16 + m16;
#pragma unroll
    for (int ks = 0; ks < 2; ks++)
      af2[mt][ks] = *(const short8*)(a1 + rl*72 + ks*32 + quad*8);
  }
  f32x4 acc2[2][2];
#pragma unroll
  for (int mt = 0; mt < 2; mt++)
#pragma unroll
    for (int nt = 0; nt < 2; nt++) acc2[mt][nt] = (f32x4){0.f,0.f,0.f,0.f};
#pragma unroll
  for (int nt = 0; nt < 2; nt++){
#pragma unroll
    for (int ks = 0; ks < 2; ks++){
      short8 b = *(const short8*)(Ws5 + (size_t)(nt*16 + m16)*72 + ks*32 + quad*8);
      acc2[0][nt] = __builtin_amdgcn_mfma_f32_16x16x32_bf16(af2[0][ks], b, acc2[0][nt], 0, 0, 0);
      acc2[1][nt] = __builtin_amdgcn_mfma_f32_16x16x32_bf16(af2[1][ks], b, acc2[1][nt], 0, 0, 0);
    }
  }
  // epilogue 2: relu -> dot P3 across 32 cols -> sigmoid
  float b0 = pb2v[m16], b1v = pb2v[16 + m16];
  float p0 = P3[m16],   p1 = P3[16 + m16];
  float pb = pb3[0];
#pragma unroll
  for (int mt = 0; mt < 2; mt++){
    float v4[4];
#pragma unroll
    for (int reg = 0; reg < 4; reg++){
      float part = fmaxf(acc2[mt][0][reg] + b0, 0.f) * p0
                 + fmaxf(acc2[mt][1][reg] + b1v, 0.f) * p1;
      part += __shfl_xor(part, 1);
      part += __shfl_xor(part, 2);
      part += __shfl_xor(part, 4);
      part += __shfl_xor(part, 8);
      v4[reg] = 1.f / (1.f + __expf(-(part + pb)));
    }
    if (m16 == 0){
      int row0 = rowb + mt*16 + quad*4;
      if (row0 + 3 < B){
        *(float4*)(outp + row0) = make_float4(v4[0], v4[1], v4[2], v4[3]);
      } else {
#pragma unroll
        for (int reg = 0; reg < 4; reg++)
          if (row0 + reg < B) outp[row0 + reg] = v4[reg];
      }
    }
  }
}

// ---------------- launcher ----------------

extern "C" void kernel_launch(void* const* d_in, const int* in_sizes, int n_in,
                              void* d_out, int out_size, void* d_ws, size_t ws_size,
                              hipStream_t stream){
  const float* ut  = (const float*)d_in[0];
  const float* it  = (const float*)d_in[1];
  const float* W1  = (const float*)d_in[2];
  const float* b1  = (const float*)d_in[3];
  const float* W2  = (const float*)d_in[4];
  const float* b2  = (const float*)d_in[5];
  const float* W3  = (const float*)d_in[6];
  const float* b3  = (const float*)d_in[7];
  const float* P1  = (const float*)d_in[8];
  const float* pb1 = (const float*)d_in[9];
  const float* P2  = (const float*)d_in[10];
  const float* pb2 = (const float*)d_in[11];
  const float* P3  = (const float*)d_in[12];
  const float* pb3 = (const float*)d_in[13];
  const int* src  = (const int*)d_in[14];
  const int* dst  = (const int*)d_in[15];
  const int* uidx = (const int*)d_in[16];
  const int* vidx = (const int*)d_in[17];

  const int NU = in_sizes[0] / 64;
  const int NI = in_sizes[1] / 64;
  const int N  = NU + NI;
  const int NE = in_sizes[14];
  const int B  = in_sizes[16];
  const int K  = (N + 255) >> 8;

  char* w = (char*)d_ws;
  auto alloc = [&](size_t bytes)->void*{
    void* p = (void*)w;
    w += (bytes + 255) & ~(size_t)255;
    return p;
  };
  float* r       = (float*)alloc((size_t)N*4);
  int*   row_ptr = (int*)  alloc((size_t)(N+1)*4);
  u32*   bhist   = (u32*)  alloc((size_t)K*4);
  u32*   bbase   = (u32*)  alloc((size_t)(K+1)*4);
  u32*   gcur    = (u32*)  alloc((size_t)K*4);
  int*   col     = (int*)  alloc((size_t)NE*4);
  u16*   Wall    = (u16*)  alloc((size_t)NWT*2);
  char*  bufE    = (char*) alloc((size_t)N*64*2 > (size_t)NE*4 ? (size_t)N*64*2 : (size_t)NE*4);
                                                      // ebuf(u32,NE) -> m1(bf16) -> x3(bf16)
  char*  bufF    = (char*) alloc((size_t)N*128*2);    // m2(bf16)
  u16*   bufC    = (u16*)  alloc((size_t)N*128*2);    // h1 -> h2
  u16*   bufD    = (u16*)  alloc((size_t)N*64*2);     // x0 -> g3
  if ((size_t)(w - (char*)d_ws) > ws_size) return;

  u16* WT1 = Wall;            // 128x64
  u16* WT2 = Wall + 8192;     // 128x128
  u16* WT3 = Wall + 24576;    // 64x128
  u16* WT4 = Wall + 32768;    // 64x128 (P1)
  u16* WT5 = Wall + 40960;    // 32x64  (P2)

  u32* ebuf = (u32*)bufE;
  u16* x0   = bufD;

  hipMemsetAsync(bhist, 0, (size_t)K*4, stream);

  int g;
  k_histK  <<<128, 256, (size_t)K*4, stream>>>(dst, NE, K, bhist, W1, W2, W3, P1, P2, Wall);
  k_scanK  <<<1, 256, 0, stream>>>(bhist, K, bbase, gcur);
  g = (NE + 4095)/4096;
  k_scatterR<<<g, 256, (size_t)K*4, stream>>>(src, dst, NE, K, gcur, ebuf);
  k_csr    <<<K, 256, 0, stream>>>(ebuf, bbase, N, NE, row_ptr, r, col, ut, it, NU, x0);

  const int ga  = (N + 3)/4;
  const int gN  = (N + 127)/128;
  const int gB  = (B + 127)/128;

  u16* m1 = (u16*)bufE;               // ebuf dead after k_csr
  k_agg<64,false><<<ga,256,0,stream>>>(x0, r, row_ptr, col, nullptr, m1, N);
  u16* h1 = bufC;
  k_mgemm<64,128,true,true,true><<<gN,256,0,stream>>>(m1, WT1, b1, r, h1, N);

  u16* m2 = (u16*)bufF;
  k_agg<128,false><<<ga,256,0,stream>>>(h1, r, row_ptr, col, nullptr, m2, N);
  u16* h2 = bufC;                     // h1 dead after agg
  k_mgemm<128,128,true,true,true><<<gN,256,0,stream>>>(m2, WT2, b2, r, h2, N);

  u16* g3 = bufD;                     // x0 dead after first agg
  k_mgemm<128,64,false,false,false><<<gN,256,0,stream>>>(h2, WT3, nullptr, nullptr, g3, N);

  u16* x3 = (u16*)bufE;               // m1 dead after GEMM1
  k_agg<64,true><<<ga,256,0,stream>>>(g3, r, row_ptr, col, b3, x3, N);

  k_mlp<<<gB,256,0,stream>>>(x3, WT4, pb1, WT5, pb2, P3, pb3, uidx, vidx, B, NU, (float*)d_out);
}